// Round 3
// baseline (151.667 us; speedup 1.0000x reference)
//
#include <hip/hip_runtime.h>

#define BB 64
#define NN 512
#define FD 64

typedef short bf16x8 __attribute__((ext_vector_type(8)));
typedef float f32x4 __attribute__((ext_vector_type(4)));

__device__ __forceinline__ unsigned short f2bf(float f){
    unsigned u = __builtin_bit_cast(unsigned, f);
    u += 0x7fffu + ((u >> 16) & 1u);           // RNE
    return (unsigned short)(u >> 16);
}
__device__ __forceinline__ float bf2f(unsigned short h){
    unsigned u = ((unsigned)h) << 16;
    return __builtin_bit_cast(float, u);
}
__device__ __forceinline__ float fast_tanh(float x){
    float e = __expf(2.0f * x);                 // inf -> 1, 0 -> -1: saturates correctly
    return 1.0f - 2.0f * __builtin_amdgcn_rcpf(e + 1.0f);
}

// colsum[d] = sum_i a[i][d];  Wt[d][c] = bf16(W[c][d])
__global__ __launch_bounds__(256) void k_prep(const float* __restrict__ W,
                                              const float* __restrict__ a,
                                              float* __restrict__ colsum,
                                              unsigned short* __restrict__ Wt){
    __shared__ float Wl[64][68];
    __shared__ float cpart[4][64];
    int t = threadIdx.x;
    int d = t & 63, part = t >> 6;
    float s = 0.f;
    #pragma unroll
    for (int i = 0; i < 16; i++) s += a[(part*16 + i)*64 + d];
    cpart[part][d] = s;
    int r = t >> 2, c0 = (t & 3) * 16;
    {
        const float4* src = (const float4*)&W[r*64 + c0];
        #pragma unroll
        for (int q = 0; q < 4; q++) *(float4*)&Wl[r][c0 + q*4] = src[q];
    }
    __syncthreads();
    if (part == 0) colsum[d] = cpart[0][d] + cpart[1][d] + cpart[2][d] + cpart[3][d];
    #pragma unroll
    for (int q = 0; q < 4; q++){
        ushort4 o;
        #pragma unroll
        for (int jj = 0; jj < 4; jj++)
            ((unsigned short*)&o)[jj] = f2bf(Wl[c0 + q*4 + jj][r]);
        *(ushort4*)&Wt[r*64 + c0 + q*4] = o;
    }
}

// XW = X @ W via MFMA; emits XWh[b][n][f] (natural) and XWt[b][f][n] (transposed), bf16
__global__ __launch_bounds__(256) void k_xw(const float* __restrict__ X,
                                            const unsigned short* __restrict__ Wt,
                                            unsigned short* __restrict__ XWh,
                                            unsigned short* __restrict__ XWt){
    __shared__ unsigned short Xl[64][72];
    __shared__ unsigned short Wtl[64][72];
    __shared__ unsigned short Cl[64][72];
    int t = threadIdx.x;
    int row0 = blockIdx.x * 64;
    int r = t >> 2, c0 = (t & 3) * 16;
    {
        const float4* src = (const float4*)&X[(row0 + r)*FD + c0];
        #pragma unroll
        for (int q = 0; q < 4; q++){
            float4 v = src[q];
            ushort4 h; h.x=f2bf(v.x); h.y=f2bf(v.y); h.z=f2bf(v.z); h.w=f2bf(v.w);
            *(ushort4*)&Xl[r][c0 + q*4] = h;
        }
        const uint4* src2 = (const uint4*)&Wt[r*64 + c0];
        *(uint4*)&Wtl[r][c0]     = src2[0];
        *(uint4*)&Wtl[r][c0 + 8] = src2[1];
    }
    __syncthreads();
    int lane = t & 63, w = t >> 6, l15 = lane & 15, quad = lane >> 4;
    f32x4 acc[4] = {{0,0,0,0},{0,0,0,0},{0,0,0,0},{0,0,0,0}};
    #pragma unroll
    for (int ks = 0; ks < 2; ks++){
        bf16x8 af = *(const bf16x8*)&Xl[w*16 + l15][ks*32 + quad*8];
        #pragma unroll
        for (int nt = 0; nt < 4; nt++){
            bf16x8 bfr = *(const bf16x8*)&Wtl[nt*16 + l15][ks*32 + quad*8];
            acc[nt] = __builtin_amdgcn_mfma_f32_16x16x32_bf16(af, bfr, acc[nt], 0, 0, 0);
        }
    }
    // transposed store straight from acc: rows rg contiguous in XWt
    int b = blockIdx.x >> 3, n0 = (blockIdx.x & 7) * 64;
    #pragma unroll
    for (int nt = 0; nt < 4; nt++){
        ushort4 hv;
        #pragma unroll
        for (int rg = 0; rg < 4; rg++) ((unsigned short*)&hv)[rg] = f2bf(acc[nt][rg]);
        *(ushort4*)&XWt[(b*64 + nt*16 + l15)*NN + n0 + w*16 + quad*4] = hv;
    }
    // natural store via LDS round trip (coalesced uint4)
    #pragma unroll
    for (int nt = 0; nt < 4; nt++)
        #pragma unroll
        for (int rg = 0; rg < 4; rg++)
            Cl[w*16 + quad*4 + rg][nt*16 + l15] = f2bf(acc[nt][rg]);
    __syncthreads();
    {
        uint4 v0 = *(const uint4*)&Cl[r][c0];
        uint4 v1 = *(const uint4*)&Cl[r][c0 + 8];
        *(uint4*)&XWh[(row0 + r)*FD + c0]     = v0;
        *(uint4*)&XWh[(row0 + r)*FD + c0 + 8] = v1;
    }
}

// Fused: M = (A_ @ XW) * diag(colsum) kept in LDS; then
// H = tanh(M @ XW^T + rowsum*bias_a) @ XW + bias_W   (flash-style over j-chunks)
__global__ __launch_bounds__(256) void k_fused(const float* __restrict__ A,
                                               const unsigned short* __restrict__ XWh,
                                               const unsigned short* __restrict__ XWt,
                                               const float* __restrict__ colsum,
                                               const int* __restrict__ Ni,
                                               const float* __restrict__ bias_a,
                                               const float* __restrict__ bias_W,
                                               float* __restrict__ H){
    __shared__ unsigned short s0[64][72];   // A chunk (phase A) / XWh chunk (phase B)
    __shared__ unsigned short s1[64][72];   // XWt chunk (phase A) / XWt chunk (phase B)
    __shared__ unsigned short Ml[64][72];
    __shared__ unsigned short Pl[64][72];
    __shared__ float rspart[64][4];
    __shared__ float rsl[64];
    __shared__ float csl[64];
    __shared__ float bl[64];
    int t = threadIdx.x;
    int b = blockIdx.y, it = blockIdx.x;
    int i0 = it * 64;
    int Nb = (Ni[1] == 0) ? Ni[2*b] : Ni[b];   // int64 vs int32 layout
    int r = t >> 2, c0 = (t & 3) * 16;
    int lane = t & 63, w = t >> 6, l15 = lane & 15, quad = lane >> 4;
    if (t < 64) csl[t] = colsum[t];
    const float* Ab = A + (b*NN + i0)*NN;

    // ---- phase A: M tile + rowsum, software-pipelined over 8 k-chunks ----
    float4 pA[4]; uint4 pB[2];
    {
        const float4* src = (const float4*)&Ab[r*NN + c0];
        #pragma unroll
        for (int q = 0; q < 4; q++) pA[q] = src[q];
        const uint4* s2 = (const uint4*)&XWt[(b*64 + r)*NN + c0];
        pB[0] = s2[0]; pB[1] = s2[1];
    }
    f32x4 acc[4] = {{0,0,0,0},{0,0,0,0},{0,0,0,0},{0,0,0,0}};
    float rs = 0.f;
    for (int c = 0; c < 8; c++){
        __syncthreads();
        #pragma unroll
        for (int q = 0; q < 4; q++){
            float4 v = pA[q];
            rs += v.x + v.y + v.z + v.w;
            ushort4 h; h.x=f2bf(v.x); h.y=f2bf(v.y); h.z=f2bf(v.z); h.w=f2bf(v.w);
            *(ushort4*)&s0[r][c0 + q*4] = h;
        }
        *(uint4*)&s1[r][c0]     = pB[0];
        *(uint4*)&s1[r][c0 + 8] = pB[1];
        __syncthreads();
        if (c < 7){   // prefetch next chunk while MFMAs run
            const float4* src = (const float4*)&Ab[r*NN + (c+1)*64 + c0];
            #pragma unroll
            for (int q = 0; q < 4; q++) pA[q] = src[q];
            const uint4* s2 = (const uint4*)&XWt[(b*64 + r)*NN + (c+1)*64 + c0];
            pB[0] = s2[0]; pB[1] = s2[1];
        }
        #pragma unroll
        for (int ks = 0; ks < 2; ks++){
            bf16x8 af = *(const bf16x8*)&s0[w*16 + l15][ks*32 + quad*8];
            #pragma unroll
            for (int nt = 0; nt < 4; nt++){
                bf16x8 bfr = *(const bf16x8*)&s1[nt*16 + l15][ks*32 + quad*8];
                acc[nt] = __builtin_amdgcn_mfma_f32_16x16x32_bf16(af, bfr, acc[nt], 0, 0, 0);
            }
        }
        if (c == it){   // diagonal of A_: adds XW[i,:] for i < Nb (k==i is in this chunk)
            #pragma unroll
            for (int nt = 0; nt < 4; nt++)
                #pragma unroll
                for (int rg = 0; rg < 4; rg++){
                    int iloc = w*16 + quad*4 + rg;
                    if (i0 + iloc < Nb)
                        acc[nt][rg] += bf2f(s1[nt*16 + l15][iloc]);
                }
        }
    }
    rspart[r][t & 3] = rs;
    // M = acc * colsum[col], into LDS in row-major (A-operand-readable) layout
    #pragma unroll
    for (int nt = 0; nt < 4; nt++){
        float cs = csl[nt*16 + l15];
        #pragma unroll
        for (int rg = 0; rg < 4; rg++)
            Ml[w*16 + quad*4 + rg][nt*16 + l15] = f2bf(acc[nt][rg] * cs);
    }
    __syncthreads();
    if (t < 64){
        float s = rspart[t][0] + rspart[t][1] + rspart[t][2] + rspart[t][3];
        if (i0 + t < Nb) s += 1.f;
        rsl[t] = s;
    }
    __syncthreads();
    bf16x8 maf[2];
    maf[0] = *(const bf16x8*)&Ml[w*16 + l15][quad*8];
    maf[1] = *(const bf16x8*)&Ml[w*16 + l15][32 + quad*8];
    float rs_r[4];
    #pragma unroll
    for (int rg = 0; rg < 4; rg++) rs_r[rg] = rsl[w*16 + quad*4 + rg];

    // ---- phase B: flash loop over 8 j-chunks, software-pipelined ----
    uint4 q1[2], q2[2];
    {
        const uint4* a1 = (const uint4*)&XWh[(b*NN + r)*FD + c0];
        q1[0] = a1[0]; q1[1] = a1[1];
        const uint4* a2 = (const uint4*)&XWt[(b*64 + r)*NN + c0];
        q2[0] = a2[0]; q2[1] = a2[1];
    }
    f32x4 hacc[4] = {{0,0,0,0},{0,0,0,0},{0,0,0,0},{0,0,0,0}};
    for (int jt = 0; jt < 8; jt++){
        __syncthreads();
        *(uint4*)&s0[r][c0]     = q1[0];
        *(uint4*)&s0[r][c0 + 8] = q1[1];
        *(uint4*)&s1[r][c0]     = q2[0];
        *(uint4*)&s1[r][c0 + 8] = q2[1];
        if (t < 64) bl[t] = bias_a[jt*64 + t];
        __syncthreads();
        if (jt < 7){
            const uint4* a1 = (const uint4*)&XWh[(b*NN + (jt+1)*64 + r)*FD + c0];
            q1[0] = a1[0]; q1[1] = a1[1];
            const uint4* a2 = (const uint4*)&XWt[(b*64 + r)*NN + (jt+1)*64 + c0];
            q2[0] = a2[0]; q2[1] = a2[1];
        }
        #pragma unroll
        for (int nt = 0; nt < 4; nt++){
            float bv = bl[nt*16 + l15];
            f32x4 arg = { rs_r[0]*bv, rs_r[1]*bv, rs_r[2]*bv, rs_r[3]*bv };
            #pragma unroll
            for (int ks = 0; ks < 2; ks++){
                bf16x8 bfr = *(const bf16x8*)&s0[nt*16 + l15][ks*32 + quad*8];
                arg = __builtin_amdgcn_mfma_f32_16x16x32_bf16(maf[ks], bfr, arg, 0, 0, 0);
            }
            #pragma unroll
            for (int rg = 0; rg < 4; rg++)
                Pl[w*16 + quad*4 + rg][nt*16 + l15] = f2bf(fast_tanh(arg[rg]));
        }
        __syncthreads();
        #pragma unroll
        for (int ks = 0; ks < 2; ks++){
            bf16x8 paf = *(const bf16x8*)&Pl[w*16 + l15][ks*32 + quad*8];
            #pragma unroll
            for (int dt = 0; dt < 4; dt++){
                bf16x8 bfr = *(const bf16x8*)&s1[dt*16 + l15][ks*32 + quad*8];
                hacc[dt] = __builtin_amdgcn_mfma_f32_16x16x32_bf16(paf, bfr, hacc[dt], 0, 0, 0);
            }
        }
    }
    #pragma unroll
    for (int dt = 0; dt < 4; dt++){
        float bw = bias_W[dt*16 + l15];
        #pragma unroll
        for (int rg = 0; rg < 4; rg++)
            H[(b*NN + i0 + w*16 + quad*4 + rg)*FD + dt*16 + l15] = hacc[dt][rg] + bw;
    }
}

extern "C" void kernel_launch(void* const* d_in, const int* in_sizes, int n_in,
                              void* d_out, int out_size, void* d_ws, size_t ws_size,
                              hipStream_t stream){
    const float* X      = (const float*)d_in[0];
    const float* A      = (const float*)d_in[1];
    const int*   N      = (const int*)  d_in[2];
    const float* W      = (const float*)d_in[3];
    const float* a      = (const float*)d_in[4];
    const float* bias_W = (const float*)d_in[5];
    const float* bias_a = (const float*)d_in[6];
    float* H = (float*)d_out;
    char* ws = (char*)d_ws;

    unsigned short* XWh    = (unsigned short*)(ws);                    // 4 MB
    unsigned short* XWt    = (unsigned short*)(ws + (4u<<20));         // 4 MB
    unsigned short* Wt     = (unsigned short*)(ws + (8u<<20));         // 8 KB
    float*          colsum = (float*)(ws + (8u<<20) + 8192);           // 256 B

    k_prep <<<1, 256, 0, stream>>>(W, a, colsum, Wt);
    k_xw   <<<BB * NN / 64, 256, 0, stream>>>(X, Wt, XWh, XWt);
    k_fused<<<dim3(8, BB), 256, 0, stream>>>(A, XWh, XWt, colsum, N, bias_a, bias_W, H);
}

// Round 4
// 130.610 us; speedup vs baseline: 1.1612x; 1.1612x over previous
//
#include <hip/hip_runtime.h>

#define BB 64
#define NN 512
#define FD 64

typedef short bf16x8 __attribute__((ext_vector_type(8)));
typedef float f32x4 __attribute__((ext_vector_type(4)));

__device__ __forceinline__ unsigned short f2bf(float f){
    unsigned u = __builtin_bit_cast(unsigned, f);
    u += 0x7fffu + ((u >> 16) & 1u);           // RNE
    return (unsigned short)(u >> 16);
}
__device__ __forceinline__ float bf2f(unsigned short h){
    unsigned u = ((unsigned)h) << 16;
    return __builtin_bit_cast(float, u);
}
__device__ __forceinline__ float fast_tanh(float x){
    float e = __expf(2.0f * x);                 // inf -> 1, 0 -> -1: saturates correctly
    return 1.0f - 2.0f * __builtin_amdgcn_rcpf(e + 1.0f);
}

// colsum[d] = sum_i a[i][d];  Wt[d][c] = bf16(W[c][d])
__global__ __launch_bounds__(256) void k_prep(const float* __restrict__ W,
                                              const float* __restrict__ a,
                                              float* __restrict__ colsum,
                                              unsigned short* __restrict__ Wt){
    __shared__ float Wl[64][68];
    __shared__ float cpart[4][64];
    int t = threadIdx.x;
    int d = t & 63, part = t >> 6;
    float s = 0.f;
    #pragma unroll
    for (int i = 0; i < 16; i++) s += a[(part*16 + i)*64 + d];
    cpart[part][d] = s;
    int r = t >> 2, c0 = (t & 3) * 16;
    {
        const float4* src = (const float4*)&W[r*64 + c0];
        #pragma unroll
        for (int q = 0; q < 4; q++) *(float4*)&Wl[r][c0 + q*4] = src[q];
    }
    __syncthreads();
    if (part == 0) colsum[d] = cpart[0][d] + cpart[1][d] + cpart[2][d] + cpart[3][d];
    #pragma unroll
    for (int q = 0; q < 4; q++){
        ushort4 o;
        #pragma unroll
        for (int jj = 0; jj < 4; jj++)
            ((unsigned short*)&o)[jj] = f2bf(Wl[c0 + q*4 + jj][r]);
        *(ushort4*)&Wt[r*64 + c0 + q*4] = o;
    }
}

// XW = X @ W via MFMA; emits XWh[b][n][f] (natural) and XWt[b][f][n] (transposed), bf16
__global__ __launch_bounds__(256) void k_xw(const float* __restrict__ X,
                                            const unsigned short* __restrict__ Wt,
                                            unsigned short* __restrict__ XWh,
                                            unsigned short* __restrict__ XWt){
    __shared__ unsigned short Xl[64][72];
    __shared__ unsigned short Wtl[64][72];
    __shared__ unsigned short Cl[64][72];    // C natural [n][f]
    __shared__ unsigned short ClT[64][72];   // C transposed [f][n]
    int t = threadIdx.x;
    int row0 = blockIdx.x * 64;
    int r = t >> 2, c0 = (t & 3) * 16;
    {
        const float4* src = (const float4*)&X[(row0 + r)*FD + c0];
        #pragma unroll
        for (int q = 0; q < 4; q++){
            float4 v = src[q];
            ushort4 h; h.x=f2bf(v.x); h.y=f2bf(v.y); h.z=f2bf(v.z); h.w=f2bf(v.w);
            *(ushort4*)&Xl[r][c0 + q*4] = h;
        }
        const uint4* src2 = (const uint4*)&Wt[r*64 + c0];
        *(uint4*)&Wtl[r][c0]     = src2[0];
        *(uint4*)&Wtl[r][c0 + 8] = src2[1];
    }
    __syncthreads();
    int lane = t & 63, w = t >> 6, l15 = lane & 15, quad = lane >> 4;
    f32x4 acc[4] = {{0,0,0,0},{0,0,0,0},{0,0,0,0},{0,0,0,0}};
    #pragma unroll
    for (int ks = 0; ks < 2; ks++){
        bf16x8 af = *(const bf16x8*)&Xl[w*16 + l15][ks*32 + quad*8];
        #pragma unroll
        for (int nt = 0; nt < 4; nt++){
            bf16x8 bfr = *(const bf16x8*)&Wtl[nt*16 + l15][ks*32 + quad*8];
            acc[nt] = __builtin_amdgcn_mfma_f32_16x16x32_bf16(af, bfr, acc[nt], 0, 0, 0);
        }
    }
    #pragma unroll
    for (int nt = 0; nt < 4; nt++)
        #pragma unroll
        for (int rg = 0; rg < 4; rg++){
            unsigned short hb = f2bf(acc[nt][rg]);
            Cl [w*16 + quad*4 + rg][nt*16 + l15] = hb;
            ClT[nt*16 + l15][w*16 + quad*4 + rg] = hb;
        }
    __syncthreads();
    int b = blockIdx.x >> 3, n0 = (blockIdx.x & 7) * 64;
    {   // natural: contiguous rows of Cl
        uint4 v0 = *(const uint4*)&Cl[r][c0];
        uint4 v1 = *(const uint4*)&Cl[r][c0 + 8];
        *(uint4*)&XWh[(row0 + r)*FD + c0]     = v0;
        *(uint4*)&XWh[(row0 + r)*FD + c0 + 8] = v1;
    }
    {   // transposed: contiguous rows of ClT -> 128B segments per 4 lanes
        uint4 v0 = *(const uint4*)&ClT[r][c0];
        uint4 v1 = *(const uint4*)&ClT[r][c0 + 8];
        *(uint4*)&XWt[(b*64 + r)*NN + n0 + c0]     = v0;
        *(uint4*)&XWt[(b*64 + r)*NN + n0 + c0 + 8] = v1;
    }
}

// Fused: M = (A_ @ XW) * diag(colsum) kept in LDS; then
// H = tanh(M @ XW^T + rowsum*bias_a) @ XW + bias_W   (flash-style over j-chunks)
// 512 threads / 8 waves: wave w -> rows (w&3)*16.., cols (w>>2)*32.. (2 MFMA tiles)
__global__ __launch_bounds__(512) void k_fused(const float* __restrict__ A,
                                               const unsigned short* __restrict__ XWh,
                                               const unsigned short* __restrict__ XWt,
                                               const float* __restrict__ colsum,
                                               const int* __restrict__ Ni,
                                               const float* __restrict__ bias_a,
                                               const float* __restrict__ bias_W,
                                               float* __restrict__ H){
    __shared__ unsigned short s0[64][72];   // A chunk (phase A) / XWh chunk (phase B)
    __shared__ unsigned short s1[64][72];   // XWt chunk (both phases)
    __shared__ unsigned short MPl[64][72];  // M tile, then reused as P tile
    __shared__ float rspart[64][8];
    __shared__ float rsl[64];
    __shared__ float csl[64];
    __shared__ float bl[64];
    int t = threadIdx.x;
    int b = blockIdx.y, it = blockIdx.x;
    int i0 = it * 64;
    int Nb = (Ni[1] == 0) ? Ni[2*b] : Ni[b];   // int64 vs int32 layout
    int r8 = t >> 3, c4 = (t & 7) * 4, c8 = (t & 7) * 8;
    int lane = t & 63, w = t >> 6, l15 = lane & 15, quad = lane >> 4;
    int wr = w & 3, wc = w >> 2;
    if (t < 64) csl[t] = colsum[t];
    const float* Ab = A + (b*NN + i0)*NN;

    // ---- phase A: M tile + rowsum, software-pipelined over 8 k-chunks ----
    float4 pA0, pA1; uint4 pB;
    pA0 = *(const float4*)&Ab[r8*NN + c4];
    pA1 = *(const float4*)&Ab[r8*NN + 32 + c4];
    pB  = *(const uint4*)&XWt[(b*64 + r8)*NN + c8];
    f32x4 acc[2] = {{0,0,0,0},{0,0,0,0}};
    float rs = 0.f;
    for (int c = 0; c < 8; c++){
        __syncthreads();
        {
            float4 v = pA0;
            rs += v.x + v.y + v.z + v.w;
            ushort4 h; h.x=f2bf(v.x); h.y=f2bf(v.y); h.z=f2bf(v.z); h.w=f2bf(v.w);
            *(ushort4*)&s0[r8][c4] = h;
            v = pA1;
            rs += v.x + v.y + v.z + v.w;
            ushort4 h2; h2.x=f2bf(v.x); h2.y=f2bf(v.y); h2.z=f2bf(v.z); h2.w=f2bf(v.w);
            *(ushort4*)&s0[r8][32 + c4] = h2;
        }
        *(uint4*)&s1[r8][c8] = pB;
        __syncthreads();
        if (c < 7){   // prefetch next chunk while MFMAs run
            pA0 = *(const float4*)&Ab[r8*NN + (c+1)*64 + c4];
            pA1 = *(const float4*)&Ab[r8*NN + (c+1)*64 + 32 + c4];
            pB  = *(const uint4*)&XWt[(b*64 + r8)*NN + (c+1)*64 + c8];
        }
        #pragma unroll
        for (int ks = 0; ks < 2; ks++){
            bf16x8 af = *(const bf16x8*)&s0[wr*16 + l15][ks*32 + quad*8];
            #pragma unroll
            for (int nt = 0; nt < 2; nt++){
                bf16x8 bfr = *(const bf16x8*)&s1[wc*32 + nt*16 + l15][ks*32 + quad*8];
                acc[nt] = __builtin_amdgcn_mfma_f32_16x16x32_bf16(af, bfr, acc[nt], 0, 0, 0);
            }
        }
        if (c == it){   // diagonal of A_: adds XW[i,:] for i < Nb (k==i is in this chunk)
            #pragma unroll
            for (int nt = 0; nt < 2; nt++)
                #pragma unroll
                for (int rg = 0; rg < 4; rg++){
                    int iloc = wr*16 + quad*4 + rg;
                    if (i0 + iloc < Nb)
                        acc[nt][rg] += bf2f(s1[wc*32 + nt*16 + l15][iloc]);
                }
        }
    }
    rspart[r8][t & 7] = rs;
    // M = acc * colsum[col] into LDS (row-major, A-operand readable)
    #pragma unroll
    for (int nt = 0; nt < 2; nt++){
        float cs = csl[wc*32 + nt*16 + l15];
        #pragma unroll
        for (int rg = 0; rg < 4; rg++)
            MPl[wr*16 + quad*4 + rg][wc*32 + nt*16 + l15] = f2bf(acc[nt][rg] * cs);
    }
    __syncthreads();
    if (t < 64){
        float s = 0.f;
        #pragma unroll
        for (int p = 0; p < 8; p++) s += rspart[t][p];
        if (i0 + t < Nb) s += 1.f;
        rsl[t] = s;
    }
    __syncthreads();
    bf16x8 maf[2];   // GEMM1 A-frags are chunk-invariant: hoist (MPl then free for P)
    maf[0] = *(const bf16x8*)&MPl[wr*16 + l15][quad*8];
    maf[1] = *(const bf16x8*)&MPl[wr*16 + l15][32 + quad*8];
    float rs_r[4];
    #pragma unroll
    for (int rg = 0; rg < 4; rg++) rs_r[rg] = rsl[wr*16 + quad*4 + rg];

    // ---- phase B: flash loop over 8 j-chunks, software-pipelined ----
    uint4 q1, q2;
    q1 = *(const uint4*)&XWh[(b*NN + r8)*FD + c8];
    q2 = *(const uint4*)&XWt[(b*64 + r8)*NN + c8];
    f32x4 hacc[2] = {{0,0,0,0},{0,0,0,0}};
    for (int jt = 0; jt < 8; jt++){
        __syncthreads();
        *(uint4*)&s0[r8][c8] = q1;
        *(uint4*)&s1[r8][c8] = q2;
        if (t < 64) bl[t] = bias_a[jt*64 + t];
        __syncthreads();
        if (jt < 7){
            q1 = *(const uint4*)&XWh[(b*NN + (jt+1)*64 + r8)*FD + c8];
            q2 = *(const uint4*)&XWt[(b*64 + r8)*NN + (jt+1)*64 + c8];
        }
        #pragma unroll
        for (int nt = 0; nt < 2; nt++){
            float bv = bl[wc*32 + nt*16 + l15];
            f32x4 arg = { rs_r[0]*bv, rs_r[1]*bv, rs_r[2]*bv, rs_r[3]*bv };
            #pragma unroll
            for (int ks = 0; ks < 2; ks++){
                bf16x8 bfr = *(const bf16x8*)&s0[wc*32 + nt*16 + l15][ks*32 + quad*8];
                arg = __builtin_amdgcn_mfma_f32_16x16x32_bf16(maf[ks], bfr, arg, 0, 0, 0);
            }
            #pragma unroll
            for (int rg = 0; rg < 4; rg++)
                MPl[wr*16 + quad*4 + rg][wc*32 + nt*16 + l15] = f2bf(fast_tanh(arg[rg]));
        }
        __syncthreads();
        #pragma unroll
        for (int ks = 0; ks < 2; ks++){
            bf16x8 paf = *(const bf16x8*)&MPl[wr*16 + l15][ks*32 + quad*8];
            #pragma unroll
            for (int dt = 0; dt < 2; dt++){
                bf16x8 bfr = *(const bf16x8*)&s1[wc*32 + dt*16 + l15][ks*32 + quad*8];
                hacc[dt] = __builtin_amdgcn_mfma_f32_16x16x32_bf16(paf, bfr, hacc[dt], 0, 0, 0);
            }
        }
    }
    #pragma unroll
    for (int dt = 0; dt < 2; dt++){
        float bw = bias_W[wc*32 + dt*16 + l15];
        #pragma unroll
        for (int rg = 0; rg < 4; rg++)
            H[(b*NN + i0 + wr*16 + quad*4 + rg)*FD + wc*32 + dt*16 + l15] = hacc[dt][rg] + bw;
    }
}

extern "C" void kernel_launch(void* const* d_in, const int* in_sizes, int n_in,
                              void* d_out, int out_size, void* d_ws, size_t ws_size,
                              hipStream_t stream){
    const float* X      = (const float*)d_in[0];
    const float* A      = (const float*)d_in[1];
    const int*   N      = (const int*)  d_in[2];
    const float* W      = (const float*)d_in[3];
    const float* a      = (const float*)d_in[4];
    const float* bias_W = (const float*)d_in[5];
    const float* bias_a = (const float*)d_in[6];
    float* H = (float*)d_out;
    char* ws = (char*)d_ws;

    unsigned short* XWh    = (unsigned short*)(ws);                    // 4 MB
    unsigned short* XWt    = (unsigned short*)(ws + (4u<<20));         // 4 MB
    unsigned short* Wt     = (unsigned short*)(ws + (8u<<20));         // 8 KB
    float*          colsum = (float*)(ws + (8u<<20) + 8192);           // 256 B

    k_prep <<<1, 256, 0, stream>>>(W, a, colsum, Wt);
    k_xw   <<<BB * NN / 64, 256, 0, stream>>>(X, Wt, XWh, XWt);
    k_fused<<<dim3(8, BB), 512, 0, stream>>>(A, XWh, XWt, colsum, N, bias_a, bias_W, H);
}